// Round 1
// baseline (638.239 us; speedup 1.0000x reference)
//
#include <hip/hip_runtime.h>

#define N_PTS   32768
#define DIMS    64
#define K_CODES 8192

// ---- d_out layout (floats, concatenated in reference return order) ----
#define OUT_ZQ      0          // 32768*64
#define OUT_IDX     2097152    // 32768 (indices stored as float)
#define OUT_LOSS    2129920    // 1
#define OUT_NEWEMB  2129921    // 8192*64
#define OUT_NCS     2654209    // 8192
#define OUT_NEWEMA  2662401    // 8192*64

// ---- d_ws layout (float offsets) ----
#define WS_COUNTS   0          // 8192
#define WS_DW       8192       // 524288
#define WS_LOSS     532480     // 1
#define WS_NSUM     532481     // 1
#define WS_NCS      532482     // 8192
#define WS_ENORM    540674     // 8192
#define WS_IDX      548866     // 32768 ints
#define WS_ZERO_BYTES (532482u * 4u)   // zero counts, dw, loss, nsum

// ============================================================
// K0: code norms ||e_k||^2
// ============================================================
__global__ __launch_bounds__(256) void enorm_kernel(const float* __restrict__ emb,
                                                    float* __restrict__ enorm) {
    int k = blockIdx.x * 256 + threadIdx.x;
    const float4* e = reinterpret_cast<const float4*>(emb + k * DIMS);
    float s = 0.0f;
#pragma unroll
    for (int i = 0; i < 16; ++i) {
        float4 v = e[i];
        s = fmaf(v.x, v.x, s);
        s = fmaf(v.y, v.y, s);
        s = fmaf(v.z, v.z, s);
        s = fmaf(v.w, v.w, s);
    }
    enorm[k] = s;
}

// ============================================================
// K1: argmin over codes.  distance proxy = sum_d(-2*z_d*e_d) + ||e||^2
// Block: 64 points x all 8192 codes (tiles of 64 codes).
// 256 threads = 16 point-groups x 16 code-groups, 4x4 register tile.
// ============================================================
__global__ __launch_bounds__(256, 2) void argmin_kernel(const float* __restrict__ z,
                                                        const float* __restrict__ emb,
                                                        const float* __restrict__ enorm,
                                                        int* __restrict__ idx_out,
                                                        float* __restrict__ idx_out_f) {
    __shared__ float As[64][64];   // [d][point]  (holds -2*z)
    __shared__ float Bs[65][64];   // [d][code], row 64 = ||e||^2
    __shared__ float redv[64][16];
    __shared__ int   redi[64][16];

    const int tid = threadIdx.x;
    const int tr = tid & 15;        // point group
    const int tc = tid >> 4;        // code group
    const int tr4 = tr * 4;
    const int tc4 = tc * 4;
    const int n0 = blockIdx.x * 64;

    // stage A transposed, scaled by -2
    {
        int n = tid >> 2;
        int q = tid & 3;
        const float4* src = reinterpret_cast<const float4*>(z + (n0 + n) * DIMS + q * 16);
#pragma unroll
        for (int i = 0; i < 4; ++i) {
            float4 v = src[i];
            int d = q * 16 + i * 4;
            As[d + 0][n] = -2.0f * v.x;
            As[d + 1][n] = -2.0f * v.y;
            As[d + 2][n] = -2.0f * v.z;
            As[d + 3][n] = -2.0f * v.w;
        }
    }

    float bestv[4];
    int   besti[4];
#pragma unroll
    for (int i = 0; i < 4; ++i) { bestv[i] = 3.4e38f; besti[i] = 0; }

    for (int k0 = 0; k0 < K_CODES; k0 += 64) {
        __syncthreads();   // protect Bs from previous iteration's readers
        {
            int kl = tid >> 2;
            int q  = tid & 3;
            const float4* src = reinterpret_cast<const float4*>(emb + (k0 + kl) * DIMS + q * 16);
#pragma unroll
            for (int i = 0; i < 4; ++i) {
                float4 v = src[i];
                int d = q * 16 + i * 4;
                Bs[d + 0][kl] = v.x;
                Bs[d + 1][kl] = v.y;
                Bs[d + 2][kl] = v.z;
                Bs[d + 3][kl] = v.w;
            }
            if (q == 0) Bs[64][kl] = enorm[k0 + kl];
        }
        __syncthreads();

        float acc[4][4] = {};
#pragma unroll
        for (int d = 0; d < 64; ++d) {
            const float4 a = *reinterpret_cast<const float4*>(&As[d][tr4]);
            const float4 b = *reinterpret_cast<const float4*>(&Bs[d][tc4]);
            float av[4] = {a.x, a.y, a.z, a.w};
            float bv[4] = {b.x, b.y, b.z, b.w};
#pragma unroll
            for (int i = 0; i < 4; ++i)
#pragma unroll
                for (int j = 0; j < 4; ++j)
                    acc[i][j] = fmaf(av[i], bv[j], acc[i][j]);
        }

        const float4 be = *reinterpret_cast<const float4*>(&Bs[64][tc4]);
        float bev[4] = {be.x, be.y, be.z, be.w};
#pragma unroll
        for (int j = 0; j < 4; ++j) {
            int kk = k0 + tc4 + j;
#pragma unroll
            for (int i = 0; i < 4; ++i) {
                float dv = acc[i][j] + bev[j];
                if (dv < bestv[i]) { bestv[i] = dv; besti[i] = kk; }
            }
        }
    }

    __syncthreads();
#pragma unroll
    for (int i = 0; i < 4; ++i) {
        redv[tr4 + i][tc] = bestv[i];
        redi[tr4 + i][tc] = besti[i];
    }
    __syncthreads();

    if (tid < 64) {
        float bv = redv[tid][0];
        int   bi = redi[tid][0];
#pragma unroll
        for (int t = 1; t < 16; ++t) {
            float v = redv[tid][t];
            int   x = redi[tid][t];
            if (v < bv || (v == bv && x < bi)) { bv = v; bi = x; }
        }
        idx_out[n0 + tid]   = bi;
        idx_out_f[n0 + tid] = (float)bi;
    }
}

// ============================================================
// K2: gather z_q, write z_q_st, accumulate counts / dw / loss
// 256 threads = 64 points x 4 chunks of 16 floats
// ============================================================
__global__ __launch_bounds__(256) void scatter_kernel(const float* __restrict__ z,
                                                      const float* __restrict__ emb,
                                                      const int* __restrict__ idx,
                                                      float* __restrict__ zq_out,
                                                      float* __restrict__ counts,
                                                      float* __restrict__ dw,
                                                      float* __restrict__ loss_accum) {
    const int tid = threadIdx.x;
    const int p = blockIdx.x * 64 + (tid >> 2);
    const int q = tid & 3;
    const int k = idx[p];

    const float4* zp = reinterpret_cast<const float4*>(z + p * DIMS + q * 16);
    const float4* ep = reinterpret_cast<const float4*>(emb + k * DIMS + q * 16);
    float4* op = reinterpret_cast<float4*>(zq_out + p * DIMS + q * 16);
    float* dwp = dw + k * DIMS + q * 16;

    float lsum = 0.0f;
#pragma unroll
    for (int i = 0; i < 4; ++i) {
        float4 zv = zp[i];
        float4 ev = ep[i];
        float4 t;
        t.x = ev.x - zv.x; t.y = ev.y - zv.y; t.z = ev.z - zv.z; t.w = ev.w - zv.w;
        lsum = fmaf(t.x, t.x, lsum);
        lsum = fmaf(t.y, t.y, lsum);
        lsum = fmaf(t.z, t.z, lsum);
        lsum = fmaf(t.w, t.w, lsum);
        float4 o;
        o.x = zv.x + t.x; o.y = zv.y + t.y; o.z = zv.z + t.z; o.w = zv.w + t.w;
        op[i] = o;
        atomicAdd(&dwp[i * 4 + 0], zv.x);
        atomicAdd(&dwp[i * 4 + 1], zv.y);
        atomicAdd(&dwp[i * 4 + 2], zv.z);
        atomicAdd(&dwp[i * 4 + 3], zv.w);
    }
    if (q == 0) atomicAdd(&counts[k], 1.0f);

    // wave-level loss reduction, one atomic per wave
#pragma unroll
    for (int o = 32; o > 0; o >>= 1) lsum += __shfl_down(lsum, o);
    if ((tid & 63) == 0) atomicAdd(loss_accum, lsum);
}

// ============================================================
// K3: new_cluster_size + accumulate n = sum(new_cluster_size)
// ============================================================
__global__ __launch_bounds__(256) void cs_kernel(const float* __restrict__ ema_cs,
                                                 const float* __restrict__ counts,
                                                 float* __restrict__ ncs_ws,
                                                 float* __restrict__ out_ncs,
                                                 float* __restrict__ n_accum) {
    const int k = blockIdx.x * 256 + threadIdx.x;
    float v = fmaf(0.99f, ema_cs[k], 0.01f * counts[k]);
    ncs_ws[k] = v;
    out_ncs[k] = v;
    float s = v;
#pragma unroll
    for (int o = 32; o > 0; o >>= 1) s += __shfl_down(s, o);
    __shared__ float ws_[4];
    if ((threadIdx.x & 63) == 0) ws_[threadIdx.x >> 6] = s;
    __syncthreads();
    if (threadIdx.x == 0) {
        float t = ws_[0] + ws_[1] + ws_[2] + ws_[3];
        atomicAdd(n_accum, t);
    }
}

// ============================================================
// K4: finalize new_ema_embedding, new_embedding, loss
// ============================================================
__global__ __launch_bounds__(256) void final_kernel(const float* __restrict__ ema_emb,
                                                    const float* __restrict__ dw,
                                                    const float* __restrict__ ncs,
                                                    const float* __restrict__ n_ptr,
                                                    const float* __restrict__ loss_ptr,
                                                    float* __restrict__ out_newemb,
                                                    float* __restrict__ out_newema,
                                                    float* __restrict__ out_loss) {
    const int i = blockIdx.x * 256 + threadIdx.x;
    const int k = i >> 6;
    const float n = *n_ptr;
    const float cs = (ncs[k] + 1e-5f) / (n + (float)K_CODES * 1e-5f) * n;
    const float ne = fmaf(0.99f, ema_emb[i], 0.01f * dw[i]);
    out_newema[i] = ne;
    out_newemb[i] = ne / cs;
    if (i == 0) {
        out_loss[0] = 0.25f * (loss_ptr[0] / 2097152.0f);
    }
}

extern "C" void kernel_launch(void* const* d_in, const int* in_sizes, int n_in,
                              void* d_out, int out_size, void* d_ws, size_t ws_size,
                              hipStream_t stream) {
    const float* z       = (const float*)d_in[0];
    const float* emb     = (const float*)d_in[1];
    const float* ema_cs  = (const float*)d_in[2];
    const float* ema_emb = (const float*)d_in[3];
    float* out = (float*)d_out;
    float* ws  = (float*)d_ws;

    float* counts  = ws + WS_COUNTS;
    float* dw      = ws + WS_DW;
    float* loss    = ws + WS_LOSS;
    float* nsum    = ws + WS_NSUM;
    float* ncs     = ws + WS_NCS;
    float* enorm   = ws + WS_ENORM;
    int*   idx     = (int*)(ws + WS_IDX);

    // zero accumulators (counts, dw, loss, nsum)
    hipMemsetAsync(d_ws, 0, WS_ZERO_BYTES, stream);

    enorm_kernel<<<K_CODES / 256, 256, 0, stream>>>(emb, enorm);

    argmin_kernel<<<N_PTS / 64, 256, 0, stream>>>(z, emb, enorm, idx, out + OUT_IDX);

    scatter_kernel<<<N_PTS / 64, 256, 0, stream>>>(z, emb, idx, out + OUT_ZQ,
                                                   counts, dw, loss);

    cs_kernel<<<K_CODES / 256, 256, 0, stream>>>(ema_cs, counts, ncs, out + OUT_NCS, nsum);

    final_kernel<<<(K_CODES * DIMS) / 256, 256, 0, stream>>>(ema_emb, dw, ncs, nsum, loss,
                                                             out + OUT_NEWEMB,
                                                             out + OUT_NEWEMA,
                                                             out + OUT_LOSS);
}

// Round 2
// 387.131 us; speedup vs baseline: 1.6486x; 1.6486x over previous
//
#include <hip/hip_runtime.h>

typedef _Float16 half8 __attribute__((ext_vector_type(8)));
typedef float f32x4 __attribute__((ext_vector_type(4)));

#define N_PTS   32768
#define DIMS    64
#define K_CODES 8192

// ---- d_out layout (floats, reference return order) ----
#define OUT_ZQ      0          // 32768*64
#define OUT_IDX     2097152    // 32768 (as float)
#define OUT_LOSS    2129920    // 1
#define OUT_NEWEMB  2129921    // 8192*64
#define OUT_NCS     2654209    // 8192
#define OUT_NEWEMA  2662401    // 8192*64

// ---- scratch inside the z_q region of d_out (written before scatter fills z_q) ----
#define SC_EHI      0          // 8192 codes * 128B f16-hi, 16B-chunk-swizzled  (262144 floats)
#define SC_ELO      262144     // f16-lo, same layout                            (262144 floats)
#define SC_ENSC     524288     // 65536*||e||^2 f32                              (8192)
#define SC_VAL1     532480     // best dist per (csplit,row)                     (4*32768)
#define SC_IDX1     663552     // best idx  (int)                                (4*32768)
#define SC_VAL2     794624     // 2nd-best dist                                  (4*32768)
#define SC_FIXLIST  925696     // rows needing exact recheck (int)               (4096)
// ends 929792 < 2097152

// ---- d_ws layout (floats) -- kept within round-1's proven footprint ----
#define WS_COUNTS   0          // 8192
#define WS_DW       8192       // 524288
#define WS_LOSS     532480
#define WS_NSUM     532481
#define WS_FIXCNT   532482     // int (+pad)
#define WS_NCS      532484     // 8192
#define WS_ENORM    540676     // 8192  (unscaled ||e||^2 for fixup)
#define WS_IDX      548868     // 32768 ints
#define WS_ZERO_BYTES (532484u * 4u)

#define MARGIN_SCALED 16.0f    // 2.4e-4 unscaled top-2 gap -> exact f32 recheck

// async global->LDS helpers (dest = wave-uniform base + lane*size)
__device__ inline void gld16(const void* g, void* l) {
    __builtin_amdgcn_global_load_lds((const __attribute__((address_space(1))) unsigned*)g,
                                     (__attribute__((address_space(3))) unsigned*)l, 16, 0, 0);
}
__device__ inline void gld4(const void* g, void* l) {
    __builtin_amdgcn_global_load_lds((const __attribute__((address_space(1))) unsigned*)g,
                                     (__attribute__((address_space(3))) unsigned*)l, 4, 0, 0);
}

// ============================================================
// K0: split codebook into f16 hi/lo (scaled by 256), swizzled 16B chunks:
// chunk c of code k stored at slot (c ^ (k&7)) so LDS ds_read_b128 is conflict-free.
// Also ||e||^2 (unscaled + 65536x scaled).
// ============================================================
__global__ __launch_bounds__(256) void esplit_kernel(const float* __restrict__ emb,
                                                     float4* __restrict__ ehi4,
                                                     float4* __restrict__ elo4,
                                                     float* __restrict__ ensc,
                                                     float* __restrict__ enorm) {
    int k = blockIdx.x * 256 + threadIdx.x;
    const float4* e4 = reinterpret_cast<const float4*>(emb + (size_t)k * DIMS);
    float vals[64];
    float sum = 0.0f;
#pragma unroll
    for (int i = 0; i < 16; ++i) {
        float4 v = e4[i];
        vals[i*4+0] = v.x; vals[i*4+1] = v.y; vals[i*4+2] = v.z; vals[i*4+3] = v.w;
        sum = fmaf(v.x, v.x, sum); sum = fmaf(v.y, v.y, sum);
        sum = fmaf(v.z, v.z, sum); sum = fmaf(v.w, v.w, sum);
    }
    enorm[k] = sum;
    ensc[k]  = 65536.0f * sum;
#pragma unroll
    for (int c = 0; c < 8; ++c) {
        union { _Float16 h[8]; float4 v; } uh, ul;
#pragma unroll
        for (int j = 0; j < 8; ++j) {
            float X = 256.0f * vals[c*8+j];
            _Float16 hh = (_Float16)X;
            uh.h[j] = hh;
            ul.h[j] = (_Float16)(X - (float)hh);
        }
        int cc = c ^ (k & 7);
        ehi4[(size_t)k*8 + cc] = uh.v;
        elo4[(size_t)k*8 + cc] = ul.v;
    }
}

// ============================================================
// K1: MFMA argmin. dist_scaled = 65536*||e||^2 + sum(A*B), A=-512*z, B=256*e.
// f16 2-split: hh + hl + lh (3 MFMAs per k-step), C init = scaled enorm.
// 512 blocks = 128 row-tiles(256 rows) x 4 code-splits(2048 codes).
// 4 waves/block, 64 rows/wave (4x 16-row subtiles), 16-code N tiles.
// Tracks per-row best (val,idx) and 2nd-best val for the margin check.
// ============================================================
__global__ __launch_bounds__(256, 2) void argmin_mfma(const float* __restrict__ z,
                                                      const char* __restrict__ ehi_g,
                                                      const char* __restrict__ elo_g,
                                                      const float* __restrict__ ensc_g,
                                                      float* __restrict__ val1,
                                                      int* __restrict__ idx1,
                                                      float* __restrict__ val2) {
    __shared__ __align__(16) char ebuf[2][2][8192];   // [buf][hi/lo][64 codes * 128B]
    __shared__ float enb[2][64];

    const int tid = threadIdx.x;
    const int w   = tid >> 6;
    const int l   = tid & 63;
    const int l15 = l & 15;
    const int l4  = l >> 4;
    const int bid = blockIdx.x;
    const int rowbase = (bid >> 2) * 256 + w * 64;
    const int c0      = (bid & 3) * 2048;

    // A fragments: 4 subtiles x 2 k-steps, hi+lo. lane: m=l&15, k=(l>>4)*8+e.
    half8 ahi[4][2], alo[4][2];
#pragma unroll
    for (int s = 0; s < 4; ++s) {
        const float* zp = z + (size_t)(rowbase + s*16 + l15) * DIMS + l4 * 8;
#pragma unroll
        for (int ks = 0; ks < 2; ++ks) {
            float4 z0 = *reinterpret_cast<const float4*>(zp + ks*32);
            float4 z1 = *reinterpret_cast<const float4*>(zp + ks*32 + 4);
            float xv[8] = {z0.x, z0.y, z0.z, z0.w, z1.x, z1.y, z1.z, z1.w};
            half8 h, lo;
#pragma unroll
            for (int j = 0; j < 8; ++j) {
                float X = -512.0f * xv[j];
                _Float16 hh = (_Float16)X;
                h[j]  = hh;
                lo[j] = (_Float16)(X - (float)hh);
            }
            ahi[s][ks] = h; alo[s][ks] = lo;
        }
    }

    float b1[16], b2[16]; int i1[16];
#pragma unroll
    for (int r = 0; r < 16; ++r) { b1[r] = 3.4e38f; b2[r] = 3.4e38f; i1[r] = 0; }

    // swizzled LDS read offsets (per k-step), tile t adds t*2048
    int rdoff[2];
#pragma unroll
    for (int ks = 0; ks < 2; ++ks)
        rdoff[ks] = l15 * 128 + (((ks*4 + l4) ^ (l15 & 7)) * 16);

    // ---- stage chunk 0 ----
    {
        const size_t gb = (size_t)c0 * 128;
        const char* sh = ehi_g + gb + tid*16;
        const char* sl = elo_g + gb + tid*16;
        char* dh = &ebuf[0][0][0] + w*1024;
        char* dl = &ebuf[0][1][0] + w*1024;
        gld16(sh,        dh);        gld16(sh + 4096, dh + 4096);
        gld16(sl,        dl);        gld16(sl + 4096, dl + 4096);
        if (w == 0) gld4(ensc_g + c0 + l, &enb[0][0]);
    }
    __syncthreads();

    int b = 0;
    for (int ch = 0; ch < 32; ++ch) {
        if (ch < 31) {   // prefetch next chunk into other buffer
            const size_t gb = (size_t)(c0 + (ch+1)*64) * 128;
            const char* sh = ehi_g + gb + tid*16;
            const char* sl = elo_g + gb + tid*16;
            char* dh = &ebuf[b^1][0][0] + w*1024;
            char* dl = &ebuf[b^1][1][0] + w*1024;
            gld16(sh,        dh);        gld16(sh + 4096, dh + 4096);
            gld16(sl,        dl);        gld16(sl + 4096, dl + 4096);
            if (w == 0) gld4(ensc_g + c0 + (ch+1)*64 + l, &enb[b^1][0]);
        }
        const char* bhbase = &ebuf[b][0][0];
        const char* blbase = &ebuf[b][1][0];
#pragma unroll
        for (int t = 0; t < 4; ++t) {
            float en = enb[b][t*16 + l15];
            half8 bh[2], bl[2];
#pragma unroll
            for (int ks = 0; ks < 2; ++ks) {
                bh[ks] = *reinterpret_cast<const half8*>(bhbase + t*2048 + rdoff[ks]);
                bl[ks] = *reinterpret_cast<const half8*>(blbase + t*2048 + rdoff[ks]);
            }
            f32x4 acc[4];
#pragma unroll
            for (int s = 0; s < 4; ++s) acc[s] = (f32x4){en, en, en, en};
#pragma unroll
            for (int ks = 0; ks < 2; ++ks) {
#pragma unroll
                for (int s = 0; s < 4; ++s)
                    acc[s] = __builtin_amdgcn_mfma_f32_16x16x32_f16(ahi[s][ks], bh[ks], acc[s], 0, 0, 0);
#pragma unroll
                for (int s = 0; s < 4; ++s)
                    acc[s] = __builtin_amdgcn_mfma_f32_16x16x32_f16(ahi[s][ks], bl[ks], acc[s], 0, 0, 0);
#pragma unroll
                for (int s = 0; s < 4; ++s)
                    acc[s] = __builtin_amdgcn_mfma_f32_16x16x32_f16(alo[s][ks], bh[ks], acc[s], 0, 0, 0);
            }
            const int code = c0 + ch*64 + t*16 + l15;
#pragma unroll
            for (int s = 0; s < 4; ++s) {
#pragma unroll
                for (int j = 0; j < 4; ++j) {
                    const int r = s*4 + j;
                    float v = acc[s][j];
                    b2[r] = fminf(b2[r], fmaxf(b1[r], v));
                    bool c = v < b1[r];
                    b1[r] = c ? v : b1[r];
                    i1[r] = c ? code : i1[r];
                }
            }
        }
        __syncthreads();
        b ^= 1;
    }

    // cross-lane merge over the 16 lanes sharing rows (xor 1,2,4,8)
#pragma unroll
    for (int m = 1; m < 16; m <<= 1) {
#pragma unroll
        for (int r = 0; r < 16; ++r) {
            float ob1 = __shfl_xor(b1[r], m, 64);
            int   oi1 = __shfl_xor(i1[r], m, 64);
            float ob2 = __shfl_xor(b2[r], m, 64);
            float nb2 = fminf(fminf(b2[r], ob2), fmaxf(b1[r], ob1));
            bool take = (ob1 < b1[r]) || (ob1 == b1[r] && oi1 < i1[r]);
            b1[r] = take ? ob1 : b1[r];
            i1[r] = take ? oi1 : i1[r];
            b2[r] = nb2;
        }
    }
    if (l15 == 0) {
        const int cs = bid & 3;
#pragma unroll
        for (int s = 0; s < 4; ++s)
#pragma unroll
            for (int j = 0; j < 4; ++j) {
                int row = rowbase + s*16 + l4*4 + j;
                int o = cs * N_PTS + row;
                val1[o] = b1[s*4+j];
                idx1[o] = i1[s*4+j];
                val2[o] = b2[s*4+j];
            }
    }
}

// ============================================================
// K2: merge the 4 code-split partials; flag rows with top-2 gap < margin
// ============================================================
__global__ __launch_bounds__(256) void combine_kernel(const float* __restrict__ val1,
                                                      const int* __restrict__ idx1,
                                                      const float* __restrict__ val2,
                                                      int* __restrict__ ws_idx,
                                                      float* __restrict__ out_idxf,
                                                      int* __restrict__ fixcnt,
                                                      int* __restrict__ fixlist) {
    int row = blockIdx.x * 256 + threadIdx.x;
    float b1 = val1[row]; int i1 = idx1[row]; float b2 = val2[row];
#pragma unroll
    for (int c = 1; c < 4; ++c) {
        float ob1 = val1[c*N_PTS + row];
        int   oi1 = idx1[c*N_PTS + row];
        float ob2 = val2[c*N_PTS + row];
        float nb2 = fminf(fminf(b2, ob2), fmaxf(b1, ob1));
        if (ob1 < b1) { b1 = ob1; i1 = oi1; }   // chunks ascend: ties keep lower idx
        b2 = nb2;
    }
    ws_idx[row]   = i1;
    out_idxf[row] = (float)i1;
    if (b2 - b1 < MARGIN_SCALED) {
        int p = atomicAdd(fixcnt, 1);
        if (p < 4096) fixlist[p] = row;
    }
}

// ============================================================
// K3: exact f32 recheck for flagged rows (expected ~10-30 rows)
// ============================================================
__global__ __launch_bounds__(256) void fixup_kernel(const float* __restrict__ z,
                                                    const float* __restrict__ emb,
                                                    const float* __restrict__ enorm,
                                                    const int* __restrict__ fixcnt,
                                                    const int* __restrict__ fixlist,
                                                    int* __restrict__ ws_idx,
                                                    float* __restrict__ out_idxf) {
    __shared__ float zrow[64];
    __shared__ float rv[256];
    __shared__ int   ri[256];
    int cnt = *fixcnt; if (cnt > 4096) cnt = 4096;
    for (int g = blockIdx.x; g < cnt; g += 64) {
        int row = fixlist[g];
        __syncthreads();
        if (threadIdx.x < 64) zrow[threadIdx.x] = z[(size_t)row * DIMS + threadIdx.x];
        __syncthreads();
        float best = 3.4e38f; int bi = 0;
        for (int k = threadIdx.x; k < K_CODES; k += 256) {
            const float4* e4 = reinterpret_cast<const float4*>(emb + (size_t)k * DIMS);
            float s = 0.0f;
#pragma unroll
            for (int i = 0; i < 16; ++i) {
                float4 ev = e4[i];
                s = fmaf(zrow[i*4+0], ev.x, s);
                s = fmaf(zrow[i*4+1], ev.y, s);
                s = fmaf(zrow[i*4+2], ev.z, s);
                s = fmaf(zrow[i*4+3], ev.w, s);
            }
            float d = fmaf(-2.0f, s, enorm[k]);
            if (d < best) { best = d; bi = k; }
        }
        rv[threadIdx.x] = best; ri[threadIdx.x] = bi;
        __syncthreads();
        for (int off = 128; off > 0; off >>= 1) {
            if (threadIdx.x < off) {
                float ov = rv[threadIdx.x + off]; int oi = ri[threadIdx.x + off];
                if (ov < rv[threadIdx.x] || (ov == rv[threadIdx.x] && oi < ri[threadIdx.x])) {
                    rv[threadIdx.x] = ov; ri[threadIdx.x] = oi;
                }
            }
            __syncthreads();
        }
        if (threadIdx.x == 0) { ws_idx[row] = ri[0]; out_idxf[row] = (float)ri[0]; }
    }
}

// ============================================================
// K4: gather z_q, write z_q_st (overwrites the scratch region), counts/dw/loss
// ============================================================
__global__ __launch_bounds__(256) void scatter_kernel(const float* __restrict__ z,
                                                      const float* __restrict__ emb,
                                                      const int* __restrict__ idx,
                                                      float* __restrict__ zq_out,
                                                      float* __restrict__ counts,
                                                      float* __restrict__ dw,
                                                      float* __restrict__ loss_accum) {
    const int tid = threadIdx.x;
    const int p = blockIdx.x * 64 + (tid >> 2);
    const int q = tid & 3;
    const int k = idx[p];

    const float4* zp = reinterpret_cast<const float4*>(z + (size_t)p * DIMS + q * 16);
    const float4* ep = reinterpret_cast<const float4*>(emb + (size_t)k * DIMS + q * 16);
    float4* op = reinterpret_cast<float4*>(zq_out + (size_t)p * DIMS + q * 16);
    float* dwp = dw + (size_t)k * DIMS + q * 16;

    float lsum = 0.0f;
#pragma unroll
    for (int i = 0; i < 4; ++i) {
        float4 zv = zp[i];
        float4 ev = ep[i];
        float4 t;
        t.x = ev.x - zv.x; t.y = ev.y - zv.y; t.z = ev.z - zv.z; t.w = ev.w - zv.w;
        lsum = fmaf(t.x, t.x, lsum); lsum = fmaf(t.y, t.y, lsum);
        lsum = fmaf(t.z, t.z, lsum); lsum = fmaf(t.w, t.w, lsum);
        float4 o;
        o.x = zv.x + t.x; o.y = zv.y + t.y; o.z = zv.z + t.z; o.w = zv.w + t.w;
        op[i] = o;
        atomicAdd(&dwp[i*4+0], zv.x);
        atomicAdd(&dwp[i*4+1], zv.y);
        atomicAdd(&dwp[i*4+2], zv.z);
        atomicAdd(&dwp[i*4+3], zv.w);
    }
    if (q == 0) atomicAdd(&counts[k], 1.0f);

#pragma unroll
    for (int o = 32; o > 0; o >>= 1) lsum += __shfl_down(lsum, o);
    if ((tid & 63) == 0) atomicAdd(loss_accum, lsum);
}

// ============================================================
// K5: new_cluster_size + n accumulation
// ============================================================
__global__ __launch_bounds__(256) void cs_kernel(const float* __restrict__ ema_cs,
                                                 const float* __restrict__ counts,
                                                 float* __restrict__ ncs_ws,
                                                 float* __restrict__ out_ncs,
                                                 float* __restrict__ n_accum) {
    const int k = blockIdx.x * 256 + threadIdx.x;
    float v = fmaf(0.99f, ema_cs[k], 0.01f * counts[k]);
    ncs_ws[k] = v;
    out_ncs[k] = v;
    float s = v;
#pragma unroll
    for (int o = 32; o > 0; o >>= 1) s += __shfl_down(s, o);
    __shared__ float ws_[4];
    if ((threadIdx.x & 63) == 0) ws_[threadIdx.x >> 6] = s;
    __syncthreads();
    if (threadIdx.x == 0) atomicAdd(n_accum, ws_[0] + ws_[1] + ws_[2] + ws_[3]);
}

// ============================================================
// K6: finalize
// ============================================================
__global__ __launch_bounds__(256) void final_kernel(const float* __restrict__ ema_emb,
                                                    const float* __restrict__ dw,
                                                    const float* __restrict__ ncs,
                                                    const float* __restrict__ n_ptr,
                                                    const float* __restrict__ loss_ptr,
                                                    float* __restrict__ out_newemb,
                                                    float* __restrict__ out_newema,
                                                    float* __restrict__ out_loss) {
    const int i = blockIdx.x * 256 + threadIdx.x;
    const int k = i >> 6;
    const float n = *n_ptr;
    const float cs = (ncs[k] + 1e-5f) / (n + (float)K_CODES * 1e-5f) * n;
    const float ne = fmaf(0.99f, ema_emb[i], 0.01f * dw[i]);
    out_newema[i] = ne;
    out_newemb[i] = ne / cs;
    if (i == 0) out_loss[0] = 0.25f * (loss_ptr[0] / 2097152.0f);
}

extern "C" void kernel_launch(void* const* d_in, const int* in_sizes, int n_in,
                              void* d_out, int out_size, void* d_ws, size_t ws_size,
                              hipStream_t stream) {
    const float* z       = (const float*)d_in[0];
    const float* emb     = (const float*)d_in[1];
    const float* ema_cs  = (const float*)d_in[2];
    const float* ema_emb = (const float*)d_in[3];
    float* out = (float*)d_out;
    float* ws  = (float*)d_ws;

    float* counts  = ws + WS_COUNTS;
    float* dw      = ws + WS_DW;
    float* loss    = ws + WS_LOSS;
    float* nsum    = ws + WS_NSUM;
    int*   fixcnt  = (int*)(ws + WS_FIXCNT);
    float* ncs     = ws + WS_NCS;
    float* enorm   = ws + WS_ENORM;
    int*   idx     = (int*)(ws + WS_IDX);

    float* ehi     = out + SC_EHI;
    float* elo     = out + SC_ELO;
    float* ensc    = out + SC_ENSC;
    float* val1    = out + SC_VAL1;
    int*   idx1    = (int*)(out + SC_IDX1);
    float* val2    = out + SC_VAL2;
    int*   fixlist = (int*)(out + SC_FIXLIST);

    hipMemsetAsync(d_ws, 0, WS_ZERO_BYTES, stream);

    esplit_kernel<<<K_CODES / 256, 256, 0, stream>>>(emb, (float4*)ehi, (float4*)elo, ensc, enorm);

    argmin_mfma<<<512, 256, 0, stream>>>(z, (const char*)ehi, (const char*)elo, ensc,
                                         val1, idx1, val2);

    combine_kernel<<<N_PTS / 256, 256, 0, stream>>>(val1, idx1, val2, idx, out + OUT_IDX,
                                                    fixcnt, fixlist);

    fixup_kernel<<<64, 256, 0, stream>>>(z, emb, enorm, fixcnt, fixlist, idx, out + OUT_IDX);

    scatter_kernel<<<N_PTS / 64, 256, 0, stream>>>(z, emb, idx, out + OUT_ZQ,
                                                   counts, dw, loss);

    cs_kernel<<<K_CODES / 256, 256, 0, stream>>>(ema_cs, counts, ncs, out + OUT_NCS, nsum);

    final_kernel<<<(K_CODES * DIMS) / 256, 256, 0, stream>>>(ema_emb, dw, ncs, nsum, loss,
                                                             out + OUT_NEWEMB,
                                                             out + OUT_NEWEMA,
                                                             out + OUT_LOSS);
}

// Round 3
// 307.201 us; speedup vs baseline: 2.0776x; 1.2602x over previous
//
#include <hip/hip_runtime.h>

typedef _Float16 half8 __attribute__((ext_vector_type(8)));
typedef float f32x4 __attribute__((ext_vector_type(4)));

#define N_PTS   32768
#define DIMS    64
#define K_CODES 8192

// ---- d_out layout (floats, reference return order) ----
#define OUT_ZQ      0          // 32768*64
#define OUT_IDX     2097152    // 32768 (as float)
#define OUT_LOSS    2129920    // 1
#define OUT_NEWEMB  2129921    // 8192*64
#define OUT_NCS     2654209    // 8192
#define OUT_NEWEMA  2662401    // 8192*64

// ---- scratch inside the z_q region of d_out (all consumed before scatter_light) ----
#define SC_EHI      0          // 262144 floats
#define SC_ELO      262144     // 262144
#define SC_ENSC     524288     // 8192
#define SC_VAL1     532480     // 4*32768
#define SC_IDX1     663552     // 4*32768 (int)
#define SC_VAL2     794624     // 4*32768
#define SC_FIXLIST  925696     // 4096 (int)
#define SC_SORTED   929792     // 32768 (int)  point ids sorted by code
#define SC_OFFSETS  962560     // 8192 (int)   exclusive prefix of counts
// ends 970752 < 2097152

// ---- d_ws layout (floats) ----
#define WS_COUNTS   0          // 8192
#define WS_CURSOR   8192       // 8192 (int)
#define WS_LOSS     16384
#define WS_NSUM     16385
#define WS_FIXCNT   16386      // int (+1 pad)
#define WS_ZERO_BYTES (16388u * 4u)
#define WS_NCS      16388      // 8192
#define WS_ENORM    24580      // 8192
#define WS_IDX      32772      // 32768 (int)
#define WS_DW       65540      // 524288
// ends 589828 floats (~2.36 MB)

#define MARGIN_SCALED 16.0f

__device__ inline void gld16(const void* g, void* l) {
    __builtin_amdgcn_global_load_lds((const __attribute__((address_space(1))) unsigned*)g,
                                     (__attribute__((address_space(3))) unsigned*)l, 16, 0, 0);
}
__device__ inline void gld4(const void* g, void* l) {
    __builtin_amdgcn_global_load_lds((const __attribute__((address_space(1))) unsigned*)g,
                                     (__attribute__((address_space(3))) unsigned*)l, 4, 0, 0);
}

// ============================================================
// K0: split codebook into f16 hi/lo (x256), 16B-chunk-swizzled; norms.
// ============================================================
__global__ __launch_bounds__(256) void esplit_kernel(const float* __restrict__ emb,
                                                     float4* __restrict__ ehi4,
                                                     float4* __restrict__ elo4,
                                                     float* __restrict__ ensc,
                                                     float* __restrict__ enorm) {
    int k = blockIdx.x * 256 + threadIdx.x;
    const float4* e4 = reinterpret_cast<const float4*>(emb + (size_t)k * DIMS);
    float vals[64];
    float sum = 0.0f;
#pragma unroll
    for (int i = 0; i < 16; ++i) {
        float4 v = e4[i];
        vals[i*4+0] = v.x; vals[i*4+1] = v.y; vals[i*4+2] = v.z; vals[i*4+3] = v.w;
        sum = fmaf(v.x, v.x, sum); sum = fmaf(v.y, v.y, sum);
        sum = fmaf(v.z, v.z, sum); sum = fmaf(v.w, v.w, sum);
    }
    enorm[k] = sum;
    ensc[k]  = 65536.0f * sum;
#pragma unroll
    for (int c = 0; c < 8; ++c) {
        union { _Float16 h[8]; float4 v; } uh, ul;
#pragma unroll
        for (int j = 0; j < 8; ++j) {
            float X = 256.0f * vals[c*8+j];
            _Float16 hh = (_Float16)X;
            uh.h[j] = hh;
            ul.h[j] = (_Float16)(X - (float)hh);
        }
        int cc = c ^ (k & 7);
        ehi4[(size_t)k*8 + cc] = uh.v;
        elo4[(size_t)k*8 + cc] = ul.v;
    }
}

// ============================================================
// K1: MFMA argmin (f16 2-split, 3 MFMA/k-step), tracks best + 2nd-best.
// ============================================================
__global__ __launch_bounds__(256, 2) void argmin_mfma(const float* __restrict__ z,
                                                      const char* __restrict__ ehi_g,
                                                      const char* __restrict__ elo_g,
                                                      const float* __restrict__ ensc_g,
                                                      float* __restrict__ val1,
                                                      int* __restrict__ idx1,
                                                      float* __restrict__ val2) {
    __shared__ __align__(16) char ebuf[2][2][8192];
    __shared__ float enb[2][64];

    const int tid = threadIdx.x;
    const int w   = tid >> 6;
    const int l   = tid & 63;
    const int l15 = l & 15;
    const int l4  = l >> 4;
    const int bid = blockIdx.x;
    const int rowbase = (bid >> 2) * 256 + w * 64;
    const int c0      = (bid & 3) * 2048;

    half8 ahi[4][2], alo[4][2];
#pragma unroll
    for (int s = 0; s < 4; ++s) {
        const float* zp = z + (size_t)(rowbase + s*16 + l15) * DIMS + l4 * 8;
#pragma unroll
        for (int ks = 0; ks < 2; ++ks) {
            float4 z0 = *reinterpret_cast<const float4*>(zp + ks*32);
            float4 z1 = *reinterpret_cast<const float4*>(zp + ks*32 + 4);
            float xv[8] = {z0.x, z0.y, z0.z, z0.w, z1.x, z1.y, z1.z, z1.w};
            half8 h, lo;
#pragma unroll
            for (int j = 0; j < 8; ++j) {
                float X = -512.0f * xv[j];
                _Float16 hh = (_Float16)X;
                h[j]  = hh;
                lo[j] = (_Float16)(X - (float)hh);
            }
            ahi[s][ks] = h; alo[s][ks] = lo;
        }
    }

    float b1[16], b2[16]; int i1[16];
#pragma unroll
    for (int r = 0; r < 16; ++r) { b1[r] = 3.4e38f; b2[r] = 3.4e38f; i1[r] = 0; }

    int rdoff[2];
#pragma unroll
    for (int ks = 0; ks < 2; ++ks)
        rdoff[ks] = l15 * 128 + (((ks*4 + l4) ^ (l15 & 7)) * 16);

    {
        const size_t gb = (size_t)c0 * 128;
        const char* sh = ehi_g + gb + tid*16;
        const char* sl = elo_g + gb + tid*16;
        char* dh = &ebuf[0][0][0] + w*1024;
        char* dl = &ebuf[0][1][0] + w*1024;
        gld16(sh,        dh);        gld16(sh + 4096, dh + 4096);
        gld16(sl,        dl);        gld16(sl + 4096, dl + 4096);
        if (w == 0) gld4(ensc_g + c0 + l, &enb[0][0]);
    }
    __syncthreads();

    int b = 0;
    for (int ch = 0; ch < 32; ++ch) {
        if (ch < 31) {
            const size_t gb = (size_t)(c0 + (ch+1)*64) * 128;
            const char* sh = ehi_g + gb + tid*16;
            const char* sl = elo_g + gb + tid*16;
            char* dh = &ebuf[b^1][0][0] + w*1024;
            char* dl = &ebuf[b^1][1][0] + w*1024;
            gld16(sh,        dh);        gld16(sh + 4096, dh + 4096);
            gld16(sl,        dl);        gld16(sl + 4096, dl + 4096);
            if (w == 0) gld4(ensc_g + c0 + (ch+1)*64 + l, &enb[b^1][0]);
        }
        const char* bhbase = &ebuf[b][0][0];
        const char* blbase = &ebuf[b][1][0];
#pragma unroll
        for (int t = 0; t < 4; ++t) {
            float en = enb[b][t*16 + l15];
            half8 bh[2], bl[2];
#pragma unroll
            for (int ks = 0; ks < 2; ++ks) {
                bh[ks] = *reinterpret_cast<const half8*>(bhbase + t*2048 + rdoff[ks]);
                bl[ks] = *reinterpret_cast<const half8*>(blbase + t*2048 + rdoff[ks]);
            }
            f32x4 acc[4];
#pragma unroll
            for (int s = 0; s < 4; ++s) acc[s] = (f32x4){en, en, en, en};
#pragma unroll
            for (int ks = 0; ks < 2; ++ks) {
#pragma unroll
                for (int s = 0; s < 4; ++s)
                    acc[s] = __builtin_amdgcn_mfma_f32_16x16x32_f16(ahi[s][ks], bh[ks], acc[s], 0, 0, 0);
#pragma unroll
                for (int s = 0; s < 4; ++s)
                    acc[s] = __builtin_amdgcn_mfma_f32_16x16x32_f16(ahi[s][ks], bl[ks], acc[s], 0, 0, 0);
#pragma unroll
                for (int s = 0; s < 4; ++s)
                    acc[s] = __builtin_amdgcn_mfma_f32_16x16x32_f16(alo[s][ks], bh[ks], acc[s], 0, 0, 0);
            }
            const int code = c0 + ch*64 + t*16 + l15;
#pragma unroll
            for (int s = 0; s < 4; ++s) {
#pragma unroll
                for (int j = 0; j < 4; ++j) {
                    const int r = s*4 + j;
                    float v = acc[s][j];
                    b2[r] = fminf(b2[r], fmaxf(b1[r], v));
                    bool c = v < b1[r];
                    b1[r] = c ? v : b1[r];
                    i1[r] = c ? code : i1[r];
                }
            }
        }
        __syncthreads();
        b ^= 1;
    }

#pragma unroll
    for (int m = 1; m < 16; m <<= 1) {
#pragma unroll
        for (int r = 0; r < 16; ++r) {
            float ob1 = __shfl_xor(b1[r], m, 64);
            int   oi1 = __shfl_xor(i1[r], m, 64);
            float ob2 = __shfl_xor(b2[r], m, 64);
            float nb2 = fminf(fminf(b2[r], ob2), fmaxf(b1[r], ob1));
            bool take = (ob1 < b1[r]) || (ob1 == b1[r] && oi1 < i1[r]);
            b1[r] = take ? ob1 : b1[r];
            i1[r] = take ? oi1 : i1[r];
            b2[r] = nb2;
        }
    }
    if (l15 == 0) {
        const int cs = bid & 3;
#pragma unroll
        for (int s = 0; s < 4; ++s)
#pragma unroll
            for (int j = 0; j < 4; ++j) {
                int row = rowbase + s*16 + l4*4 + j;
                int o = cs * N_PTS + row;
                val1[o] = b1[s*4+j];
                idx1[o] = i1[s*4+j];
                val2[o] = b2[s*4+j];
            }
    }
}

// ============================================================
// K2: merge code-split partials; flag narrow-margin rows
// ============================================================
__global__ __launch_bounds__(256) void combine_kernel(const float* __restrict__ val1,
                                                      const int* __restrict__ idx1,
                                                      const float* __restrict__ val2,
                                                      int* __restrict__ ws_idx,
                                                      float* __restrict__ out_idxf,
                                                      int* __restrict__ fixcnt,
                                                      int* __restrict__ fixlist) {
    int row = blockIdx.x * 256 + threadIdx.x;
    float b1 = val1[row]; int i1 = idx1[row]; float b2 = val2[row];
#pragma unroll
    for (int c = 1; c < 4; ++c) {
        float ob1 = val1[c*N_PTS + row];
        int   oi1 = idx1[c*N_PTS + row];
        float ob2 = val2[c*N_PTS + row];
        float nb2 = fminf(fminf(b2, ob2), fmaxf(b1, ob1));
        if (ob1 < b1) { b1 = ob1; i1 = oi1; }
        b2 = nb2;
    }
    ws_idx[row]   = i1;
    out_idxf[row] = (float)i1;
    if (b2 - b1 < MARGIN_SCALED) {
        int p = atomicAdd(fixcnt, 1);
        if (p < 4096) fixlist[p] = row;
    }
}

// ============================================================
// K3: exact f32 recheck for flagged rows
// ============================================================
__global__ __launch_bounds__(256) void fixup_kernel(const float* __restrict__ z,
                                                    const float* __restrict__ emb,
                                                    const float* __restrict__ enorm,
                                                    const int* __restrict__ fixcnt,
                                                    const int* __restrict__ fixlist,
                                                    int* __restrict__ ws_idx,
                                                    float* __restrict__ out_idxf) {
    __shared__ float zrow[64];
    __shared__ float rv[256];
    __shared__ int   ri[256];
    int cnt = *fixcnt; if (cnt > 4096) cnt = 4096;
    for (int g = blockIdx.x; g < cnt; g += 64) {
        int row = fixlist[g];
        __syncthreads();
        if (threadIdx.x < 64) zrow[threadIdx.x] = z[(size_t)row * DIMS + threadIdx.x];
        __syncthreads();
        float best = 3.4e38f; int bi = 0;
        for (int k = threadIdx.x; k < K_CODES; k += 256) {
            const float4* e4 = reinterpret_cast<const float4*>(emb + (size_t)k * DIMS);
            float s = 0.0f;
#pragma unroll
            for (int i = 0; i < 16; ++i) {
                float4 ev = e4[i];
                s = fmaf(zrow[i*4+0], ev.x, s);
                s = fmaf(zrow[i*4+1], ev.y, s);
                s = fmaf(zrow[i*4+2], ev.z, s);
                s = fmaf(zrow[i*4+3], ev.w, s);
            }
            float d = fmaf(-2.0f, s, enorm[k]);
            if (d < best) { best = d; bi = k; }
        }
        rv[threadIdx.x] = best; ri[threadIdx.x] = bi;
        __syncthreads();
        for (int off = 128; off > 0; off >>= 1) {
            if (threadIdx.x < off) {
                float ov = rv[threadIdx.x + off]; int oi = ri[threadIdx.x + off];
                if (ov < rv[threadIdx.x] || (ov == rv[threadIdx.x] && oi < ri[threadIdx.x])) {
                    rv[threadIdx.x] = ov; ri[threadIdx.x] = oi;
                }
            }
            __syncthreads();
        }
        if (threadIdx.x == 0) { ws_idx[row] = ri[0]; out_idxf[row] = (float)ri[0]; }
    }
}

// ============================================================
// K4: histogram of final indices
// ============================================================
__global__ __launch_bounds__(256) void hist_kernel(const int* __restrict__ idx,
                                                   float* __restrict__ counts) {
    int p = blockIdx.x * 256 + threadIdx.x;
    atomicAdd(&counts[idx[p]], 1.0f);
}

// ============================================================
// K5: exclusive scan of counts -> offsets (single block)
// ============================================================
__global__ __launch_bounds__(256) void scan_kernel(const float* __restrict__ counts,
                                                   int* __restrict__ offsets) {
    __shared__ int excl[256];
    const int t = threadIdx.x;
    const int base = t * 32;
    int local[32];
    int s = 0;
#pragma unroll
    for (int i = 0; i < 32; ++i) { local[i] = s; s += (int)counts[base + i]; }
    __shared__ int tot[256];
    tot[t] = s;
    __syncthreads();
    if (t == 0) {
        int r = 0;
#pragma unroll 8
        for (int i = 0; i < 256; ++i) { excl[i] = r; r += tot[i]; }
    }
    __syncthreads();
    const int off = excl[t];
#pragma unroll
    for (int i = 0; i < 32; ++i) offsets[base + i] = off + local[i];
}

// ============================================================
// K6: place point ids into code-sorted order
// ============================================================
__global__ __launch_bounds__(256) void place_kernel(const int* __restrict__ idx,
                                                    const int* __restrict__ offsets,
                                                    int* __restrict__ cursor,
                                                    int* __restrict__ sorted) {
    int p = blockIdx.x * 256 + threadIdx.x;
    int k = idx[p];
    int pos = offsets[k] + atomicAdd(&cursor[k], 1);
    sorted[pos] = p;
}

// ============================================================
// K7: dw[k] = sum of z rows in segment k. One wave per code, lane = dim.
// ============================================================
__global__ __launch_bounds__(256) void dw_kernel(const float* __restrict__ z,
                                                 const int* __restrict__ sorted,
                                                 const int* __restrict__ offsets,
                                                 const float* __restrict__ counts,
                                                 float* __restrict__ dw) {
    const int w = threadIdx.x >> 6;
    const int lane = threadIdx.x & 63;
    const int k = blockIdx.x * 4 + w;
    const int start = offsets[k];
    const int cnt = (int)counts[k];
    float s = 0.0f;
    for (int i = 0; i < cnt; ++i) {
        int p = sorted[start + i];
        s += z[(size_t)p * DIMS + lane];
    }
    dw[(size_t)k * DIMS + lane] = s;
}

// ============================================================
// K8: gather z_q, write z_q_st, loss (no dw atomics anymore)
// ============================================================
__global__ __launch_bounds__(256) void scatter_light(const float* __restrict__ z,
                                                     const float* __restrict__ emb,
                                                     const int* __restrict__ idx,
                                                     float* __restrict__ zq_out,
                                                     float* __restrict__ loss_accum) {
    const int tid = threadIdx.x;
    const int p = blockIdx.x * 64 + (tid >> 2);
    const int q = tid & 3;
    const int k = idx[p];

    const float4* zp = reinterpret_cast<const float4*>(z + (size_t)p * DIMS + q * 16);
    const float4* ep = reinterpret_cast<const float4*>(emb + (size_t)k * DIMS + q * 16);
    float4* op = reinterpret_cast<float4*>(zq_out + (size_t)p * DIMS + q * 16);

    float lsum = 0.0f;
#pragma unroll
    for (int i = 0; i < 4; ++i) {
        float4 zv = zp[i];
        float4 ev = ep[i];
        float4 t;
        t.x = ev.x - zv.x; t.y = ev.y - zv.y; t.z = ev.z - zv.z; t.w = ev.w - zv.w;
        lsum = fmaf(t.x, t.x, lsum); lsum = fmaf(t.y, t.y, lsum);
        lsum = fmaf(t.z, t.z, lsum); lsum = fmaf(t.w, t.w, lsum);
        float4 o;
        o.x = zv.x + t.x; o.y = zv.y + t.y; o.z = zv.z + t.z; o.w = zv.w + t.w;
        op[i] = o;
    }
#pragma unroll
    for (int o = 32; o > 0; o >>= 1) lsum += __shfl_down(lsum, o);
    if ((tid & 63) == 0) atomicAdd(loss_accum, lsum);
}

// ============================================================
// K9: new_cluster_size + n accumulation
// ============================================================
__global__ __launch_bounds__(256) void cs_kernel(const float* __restrict__ ema_cs,
                                                 const float* __restrict__ counts,
                                                 float* __restrict__ ncs_ws,
                                                 float* __restrict__ out_ncs,
                                                 float* __restrict__ n_accum) {
    const int k = blockIdx.x * 256 + threadIdx.x;
    float v = fmaf(0.99f, ema_cs[k], 0.01f * counts[k]);
    ncs_ws[k] = v;
    out_ncs[k] = v;
    float s = v;
#pragma unroll
    for (int o = 32; o > 0; o >>= 1) s += __shfl_down(s, o);
    __shared__ float ws_[4];
    if ((threadIdx.x & 63) == 0) ws_[threadIdx.x >> 6] = s;
    __syncthreads();
    if (threadIdx.x == 0) atomicAdd(n_accum, ws_[0] + ws_[1] + ws_[2] + ws_[3]);
}

// ============================================================
// K10: finalize
// ============================================================
__global__ __launch_bounds__(256) void final_kernel(const float* __restrict__ ema_emb,
                                                    const float* __restrict__ dw,
                                                    const float* __restrict__ ncs,
                                                    const float* __restrict__ n_ptr,
                                                    const float* __restrict__ loss_ptr,
                                                    float* __restrict__ out_newemb,
                                                    float* __restrict__ out_newema,
                                                    float* __restrict__ out_loss) {
    const int i = blockIdx.x * 256 + threadIdx.x;
    const int k = i >> 6;
    const float n = *n_ptr;
    const float cs = (ncs[k] + 1e-5f) / (n + (float)K_CODES * 1e-5f) * n;
    const float ne = fmaf(0.99f, ema_emb[i], 0.01f * dw[i]);
    out_newema[i] = ne;
    out_newemb[i] = ne / cs;
    if (i == 0) out_loss[0] = 0.25f * (loss_ptr[0] / 2097152.0f);
}

extern "C" void kernel_launch(void* const* d_in, const int* in_sizes, int n_in,
                              void* d_out, int out_size, void* d_ws, size_t ws_size,
                              hipStream_t stream) {
    const float* z       = (const float*)d_in[0];
    const float* emb     = (const float*)d_in[1];
    const float* ema_cs  = (const float*)d_in[2];
    const float* ema_emb = (const float*)d_in[3];
    float* out = (float*)d_out;
    float* ws  = (float*)d_ws;

    float* counts  = ws + WS_COUNTS;
    int*   cursor  = (int*)(ws + WS_CURSOR);
    float* loss    = ws + WS_LOSS;
    float* nsum    = ws + WS_NSUM;
    int*   fixcnt  = (int*)(ws + WS_FIXCNT);
    float* ncs     = ws + WS_NCS;
    float* enorm   = ws + WS_ENORM;
    int*   idx     = (int*)(ws + WS_IDX);
    float* dw      = ws + WS_DW;

    float* ehi     = out + SC_EHI;
    float* elo     = out + SC_ELO;
    float* ensc    = out + SC_ENSC;
    float* val1    = out + SC_VAL1;
    int*   idx1    = (int*)(out + SC_IDX1);
    float* val2    = out + SC_VAL2;
    int*   fixlist = (int*)(out + SC_FIXLIST);
    int*   sorted  = (int*)(out + SC_SORTED);
    int*   offsets = (int*)(out + SC_OFFSETS);

    hipMemsetAsync(d_ws, 0, WS_ZERO_BYTES, stream);

    esplit_kernel<<<K_CODES / 256, 256, 0, stream>>>(emb, (float4*)ehi, (float4*)elo, ensc, enorm);

    argmin_mfma<<<512, 256, 0, stream>>>(z, (const char*)ehi, (const char*)elo, ensc,
                                         val1, idx1, val2);

    combine_kernel<<<N_PTS / 256, 256, 0, stream>>>(val1, idx1, val2, idx, out + OUT_IDX,
                                                    fixcnt, fixlist);

    fixup_kernel<<<64, 256, 0, stream>>>(z, emb, enorm, fixcnt, fixlist, idx, out + OUT_IDX);

    hist_kernel<<<N_PTS / 256, 256, 0, stream>>>(idx, counts);

    scan_kernel<<<1, 256, 0, stream>>>(counts, offsets);

    place_kernel<<<N_PTS / 256, 256, 0, stream>>>(idx, offsets, cursor, sorted);

    dw_kernel<<<K_CODES / 4, 256, 0, stream>>>(z, sorted, offsets, counts, dw);

    scatter_light<<<N_PTS / 64, 256, 0, stream>>>(z, emb, idx, out + OUT_ZQ, loss);

    cs_kernel<<<K_CODES / 256, 256, 0, stream>>>(ema_cs, counts, ncs, out + OUT_NCS, nsum);

    final_kernel<<<(K_CODES * DIMS) / 256, 256, 0, stream>>>(ema_emb, dw, ncs, nsum, loss,
                                                             out + OUT_NEWEMB,
                                                             out + OUT_NEWEMA,
                                                             out + OUT_LOSS);
}